// Round 8
// baseline (333.743 us; speedup 1.0000x reference)
//
#include <hip/hip_runtime.h>

#define DD 1024
#define HALO 32
#define IMGF (2 * (HALO + DD + HALO))   // floats per interleaved row image = 2176 = 17*128
#define HALF_DT_F 0.05f
#define CG_ITERS_N 20

typedef float f2 __attribute__((ext_vector_type(2)));   // (re, im) -> v_pk_* ops

// XOR swizzle on float index (byte' = byte ^ (((byte>>7)&3)<<4)).
// Involution; preserves 16B alignment; commutes with any offset that is a
// multiple of 128 floats (512B): IMGF row base and +-2*DD halo shifts qualify.
// 8 consecutive lanes (64B stride) -> 8 distinct 4-bank groups.
__device__ __forceinline__ int swzf(int f) { return f ^ (((f >> 5) & 3) << 2); }

// Wave64 sum via DPP (pure VALU). Total valid in lane 63 ONLY.
__device__ __forceinline__ float dpp_wave_sum(float v) {
    int b;
    b = __builtin_amdgcn_update_dpp(0, __float_as_int(v), 0x111, 0xf, 0xf, true); v += __int_as_float(b); // row_shr:1
    b = __builtin_amdgcn_update_dpp(0, __float_as_int(v), 0x112, 0xf, 0xf, true); v += __int_as_float(b); // row_shr:2
    b = __builtin_amdgcn_update_dpp(0, __float_as_int(v), 0x114, 0xf, 0xf, true); v += __int_as_float(b); // row_shr:4
    b = __builtin_amdgcn_update_dpp(0, __float_as_int(v), 0x118, 0xf, 0xf, true); v += __int_as_float(b); // row_shr:8
    b = __builtin_amdgcn_update_dpp(0, __float_as_int(v), 0x142, 0xa, 0xf, true); v += __int_as_float(b); // row_bcast:15
    b = __builtin_amdgcn_update_dpp(0, __float_as_int(v), 0x143, 0xc, 0xf, true); v += __int_as_float(b); // row_bcast:31
    return v;
}

// Row-wide (128-thread, 2-wave) sum; exactly one barrier. Caller alternates
// `red` buffers so consecutive reductions never reuse a live buffer.
__device__ __forceinline__ float row_sum(float v, float* red, int wave, int rw) {
    v = dpp_wave_sum(v);
    if ((threadIdx.x & 63) == 63) red[wave] = v;
    __syncthreads();
    return red[2 * rw] + red[2 * rw + 1];
}

// Packed H-apply on this thread's 8 complex elements (center passed in regs).
// Two passes (left 20 neighbors, right 20 neighbors), 10 b128 reads each.
__device__ __forceinline__ void hmat8p(const float* lds, const int raL[10], const int raR[10],
                                       const float cw[11], const float diag[8],
                                       const f2 pc[8], f2 H[8]) {
    constexpr int taps[11] = {1, 2, 3, 4, 5, 6, 8, 10, 12, 16, 20};
    {   // ---- pass L: left window [d0-20, d0) + all center-resident taps ----
        f2 lw[20];
#pragma unroll
        for (int k = 0; k < 10; ++k) {
            float4 v = *reinterpret_cast<const float4*>(&lds[raL[k]]);
            lw[2 * k] = f2{v.x, v.y};
            lw[2 * k + 1] = f2{v.z, v.w};
        }
#pragma unroll
        for (int i = 0; i < 8; ++i) {
            f2 acc = diag[i] * pc[i];
#pragma unroll
            for (int j = 0; j < 11; ++j) {
                const int n = i - taps[j];
                const f2 vl = (n >= 0) ? pc[n] : lw[20 + n];
                acc -= cw[j] * vl;
                const int m = i + taps[j];
                if (m <= 7) acc -= cw[j] * pc[m];
            }
            H[i] = acc;
        }
    }
    {   // ---- pass R: right window (d0+7, d0+28) ----
        f2 rw2[20];
#pragma unroll
        for (int k = 0; k < 10; ++k) {
            float4 v = *reinterpret_cast<const float4*>(&lds[raR[k]]);
            rw2[2 * k] = f2{v.x, v.y};
            rw2[2 * k + 1] = f2{v.z, v.w};
        }
#pragma unroll
        for (int i = 0; i < 8; ++i) {
            f2 acc = H[i];
#pragma unroll
            for (int j = 0; j < 11; ++j) {
                const int m = i + taps[j];
                if (m > 7) acc -= cw[j] * rw2[m - 8];
            }
            H[i] = acc;
        }
    }
}

// Store this thread's 8 interleaved complex (4 float4) + halo copies
// (row-threads 0..3 duplicate right, 124..127 left).
__device__ __forceinline__ void store_row8p(float* lds, const int wa[4], const int ha[4],
                                            bool hh, const f2 v[8]) {
#pragma unroll
    for (int j = 0; j < 4; ++j) {
        float4 a = make_float4(v[2 * j].x, v[2 * j].y, v[2 * j + 1].x, v[2 * j + 1].y);
        *reinterpret_cast<float4*>(&lds[wa[j]]) = a;
        if (hh) *reinterpret_cast<float4*>(&lds[ha[j]]) = a;
    }
}

__global__ void __launch_bounds__(256, 2)
cayley_kernel(const float* __restrict__ psi_r, const float* __restrict__ psi_i,
              const float* __restrict__ alpha, const float* __restrict__ sw,
              const float* __restrict__ potential, float* __restrict__ out) {
    __shared__ __align__(16) float lds[2 * IMGF];   // 2 rows, interleaved complex
    __shared__ float red0[4], red1[4];

    const int t = threadIdx.x;
    const int u = t & 127;         // row-local thread: owns complex [8u, 8u+8)
    const int rw = t >> 7;         // row within block (0/1)
    const int wave = t >> 6;
    const int rb = rw * IMGF;
    const int row = (blockIdx.x << 1) + rw;

    const float w0 = sw[0], w1 = sw[1], w2 = sw[2];   // uniform -> SGPRs
    const float cw[11] = {w0, w0 + w1, w0, w0 + w1 + w2, w0, w1, w1 + w2, w1, w2, w2, w2};
    const float dadd = 10.0f * (w0 + w1 + w2);

    // Loop-invariant swizzled LDS float-index addresses.
    const int fb = rb + 2 * (HALO + 8 * u);   // float index of this thread's first complex
    int wa[4], raL[10], raR[10];
#pragma unroll
    for (int j = 0; j < 4; ++j) wa[j] = swzf(fb + 4 * j);
#pragma unroll
    for (int k = 0; k < 10; ++k) {
        raL[k] = swzf(fb - 40 + 4 * k);       // left 20 complex
        raR[k] = swzf(fb + 16 + 4 * k);       // right 20 complex
    }
    const bool hh = (u < 4) || (u >= 124);
    int ha[4] = {0, 0, 0, 0};
    if (u < 4) {
#pragma unroll
        for (int j = 0; j < 4; ++j) ha[j] = swzf(fb + 2 * DD + 4 * j);
    } else if (u >= 124) {
#pragma unroll
        for (int j = 0; j < 4; ++j) ha[j] = swzf(fb - 2 * DD + 4 * j);
    }

    // --- global loads: 8 complex per thread (planar in, packed regs) ---
    const size_t goff = (size_t)row * DD + 8 * u;
    f2 cur[8];
    float diag[8];
#pragma unroll
    for (int j = 0; j < 2; ++j) {
        float4 a = *reinterpret_cast<const float4*>(psi_r + goff + 4 * j);
        float4 b = *reinterpret_cast<const float4*>(psi_i + goff + 4 * j);
        float4 d = *reinterpret_cast<const float4*>(potential + 8 * u + 4 * j);
        cur[4 * j + 0] = f2{a.x, b.x};
        cur[4 * j + 1] = f2{a.y, b.y};
        cur[4 * j + 2] = f2{a.z, b.z};
        cur[4 * j + 3] = f2{a.w, b.w};
        diag[4 * j] = d.x + dadd; diag[4 * j + 1] = d.y + dadd;
        diag[4 * j + 2] = d.z + dadd; diag[4 * j + 3] = d.w + dadd;
    }

    // --- intensity mean over the row ---
    float isum = 0.f;
#pragma unroll
    for (int i = 0; i < 8; ++i) isum += cur[i].x * cur[i].x + cur[i].y * cur[i].y;
    const float tot = row_sum(isum, red0, wave, rw);
    const float inv_mean = 1.0f / (tot * (1.0f / DD) + 1e-8f);

    // --- nonlinear phase rotation (in place) ---
#pragma unroll
    for (int j = 0; j < 2; ++j) {
        float4 c = *reinterpret_cast<const float4*>(alpha + 8 * u + 4 * j);
        float av[4] = {c.x, c.y, c.z, c.w};
#pragma unroll
        for (int q = 0; q < 4; ++q) {
            const int i = 4 * j + q;
            const float ph = av[q] * ((cur[i].x * cur[i].x + cur[i].y * cur[i].y) * inv_mean);
            float s, cc;
            __sincosf(ph, &s, &cc);
            cur[i] = f2{cur[i].x * cc - cur[i].y * s, cur[i].x * s + cur[i].y * cc};
        }
    }

    store_row8p(lds, wa, ha, hh, cur);
    __syncthreads();

    // --- b = (I - i*h*H) rot ; r = p = b ; x = 0 ---
    f2 H2[8];
    hmat8p(lds, raL, raR, cw, diag, cur, H2);

    f2 x2[8], r2[8], p2[8], hp2[8];
    float rsum = 0.f;
#pragma unroll
    for (int i = 0; i < 8; ++i) {
        x2[i] = f2{0.f, 0.f};
        r2[i] = f2{cur[i].x + HALF_DT_F * H2[i].y, cur[i].y - HALF_DT_F * H2[i].x};
        p2[i] = r2[i];
        rsum += r2[i].x * r2[i].x + r2[i].y * r2[i].y;
    }
    float rs = row_sum(rsum, red1, wave, rw);   // barrier: also fences rot-window reads

    store_row8p(lds, wa, ha, hh, r2);           // r image (= p0 = b)
    __syncthreads();

    hmat8p(lds, raL, raR, cw, diag, p2, hp2);   // hp = H(p0)

    // --- CG with H-linearity recurrence: hp_new = H(r) + beta*hp ---
    // 2 barriers/iter (the rs reduction doubles as the r-store fence);
    // final iteration needs only the pAp reduction.
#pragma unroll 1
    for (int it = 0; it < CG_ITERS_N; ++it) {
        // pAp = sum p.(p - i*h*hp), Ap never materialized
        float pap = 0.f;
#pragma unroll
        for (int i = 0; i < 8; ++i)
            pap += p2[i].x * p2[i].x + p2[i].y * p2[i].y
                 - HALF_DT_F * (p2[i].x * hp2[i].y - p2[i].y * hp2[i].x);
        const float pAp = row_sum(pap, red0, wave, rw);   // barrier #1 (fences r-window reads)
        const float al = rs / (pAp + 1e-12f);
        const float alh = al * HALF_DT_F;

#pragma unroll
        for (int i = 0; i < 8; ++i) x2[i] += al * p2[i];

        if (it == CG_ITERS_N - 1) break;    // x final; r/beta/matvec not needed

        float rnew = 0.f;
#pragma unroll
        for (int i = 0; i < 8; ++i) {
            r2[i] = f2{r2[i].x - al * p2[i].x + alh * hp2[i].y,
                       r2[i].y - al * p2[i].y - alh * hp2[i].x};
            rnew += r2[i].x * r2[i].x + r2[i].y * r2[i].y;
        }
        store_row8p(lds, wa, ha, hh, r2);                 // issue stores, then reduce
        const float rs_new = row_sum(rnew, red1, wave, rw);   // barrier #2 (fences stores)
        const float beta = rs_new / (rs + 1e-12f);
        rs = rs_new;

        f2 hr2[8];
        hmat8p(lds, raL, raR, cw, diag, r2, hr2);         // H(r), reads fenced by barrier #2
#pragma unroll
        for (int i = 0; i < 8; ++i) {
            p2[i] = r2[i] + beta * p2[i];
            hp2[i] = hr2[i] + beta * hp2[i];
        }
    }

    // --- write x: output layout [.., D, 2] is exactly our packed layout ---
    float* op = out + 2 * goff;
#pragma unroll
    for (int j = 0; j < 4; ++j) {
        *reinterpret_cast<float4*>(op + 4 * j) =
            make_float4(x2[2 * j].x, x2[2 * j].y, x2[2 * j + 1].x, x2[2 * j + 1].y);
    }
}

extern "C" void kernel_launch(void* const* d_in, const int* in_sizes, int n_in,
                              void* d_out, int out_size, void* d_ws, size_t ws_size,
                              hipStream_t stream) {
    const float* psi_r = (const float*)d_in[0];
    const float* psi_i = (const float*)d_in[1];
    const float* alpha = (const float*)d_in[2];
    const float* sw = (const float*)d_in[3];
    const float* pot = (const float*)d_in[4];
    float* out = (float*)d_out;
    const int rows = in_sizes[0] / DD;   // B*S = 8192
    cayley_kernel<<<dim3(rows / 2), dim3(256), 0, stream>>>(psi_r, psi_i, alpha, sw, pot, out);
}

// Round 9
// 290.383 us; speedup vs baseline: 1.1493x; 1.1493x over previous
//
#include <hip/hip_runtime.h>

#define DD 1024
#define HALO 32
#define IMGF (2 * (HALO + DD + HALO))   // floats per interleaved row image = 2176 = 17*128
#define HALF_DT_F 0.05f
#define CG_ITERS_N 20

typedef float f2 __attribute__((ext_vector_type(2)));   // (re, im) -> v_pk_* ops

// XOR swizzle on float index (byte' = byte ^ (((byte>>7)&3)<<4)).
// Involution; preserves 16B alignment; commutes with any offset that is a
// multiple of 128 floats (512B): +-2*DD halo shifts qualify.
// 8 consecutive lanes (64B stride) -> 8 distinct 4-bank groups.
__device__ __forceinline__ int swzf(int f) { return f ^ (((f >> 5) & 3) << 2); }

// Wave64 sum via DPP (pure VALU). Total valid in lane 63 ONLY.
__device__ __forceinline__ float dpp_wave_sum(float v) {
    int b;
    b = __builtin_amdgcn_update_dpp(0, __float_as_int(v), 0x111, 0xf, 0xf, true); v += __int_as_float(b); // row_shr:1
    b = __builtin_amdgcn_update_dpp(0, __float_as_int(v), 0x112, 0xf, 0xf, true); v += __int_as_float(b); // row_shr:2
    b = __builtin_amdgcn_update_dpp(0, __float_as_int(v), 0x114, 0xf, 0xf, true); v += __int_as_float(b); // row_shr:4
    b = __builtin_amdgcn_update_dpp(0, __float_as_int(v), 0x118, 0xf, 0xf, true); v += __int_as_float(b); // row_shr:8
    b = __builtin_amdgcn_update_dpp(0, __float_as_int(v), 0x142, 0xa, 0xf, true); v += __int_as_float(b); // row_bcast:15
    b = __builtin_amdgcn_update_dpp(0, __float_as_int(v), 0x143, 0xc, 0xf, true); v += __int_as_float(b); // row_bcast:31
    return v;
}

// Block-wide (128-thread, 2-wave) sum; exactly one barrier. Caller alternates
// `red` buffers so consecutive reductions never reuse a live buffer.
__device__ __forceinline__ float row_sum(float v, float* red, int wave) {
    v = dpp_wave_sum(v);
    if ((threadIdx.x & 63) == 63) red[wave] = v;
    __syncthreads();
    return red[0] + red[1];
}

// Packed H-apply on this thread's 8 complex elements (center passed in regs).
// Two passes (left 20 neighbors, right 20 neighbors), 10 b128 reads each.
__device__ __forceinline__ void hmat8p(const float* lds, const int raL[10], const int raR[10],
                                       const float cw[11], const float diag[8],
                                       const f2 pc[8], f2 H[8]) {
    constexpr int taps[11] = {1, 2, 3, 4, 5, 6, 8, 10, 12, 16, 20};
    {   // ---- pass L: left window [d0-20, d0) + all center-resident taps ----
        f2 lw[20];
#pragma unroll
        for (int k = 0; k < 10; ++k) {
            float4 v = *reinterpret_cast<const float4*>(&lds[raL[k]]);
            lw[2 * k] = f2{v.x, v.y};
            lw[2 * k + 1] = f2{v.z, v.w};
        }
#pragma unroll
        for (int i = 0; i < 8; ++i) {
            f2 acc = diag[i] * pc[i];
#pragma unroll
            for (int j = 0; j < 11; ++j) {
                const int n = i - taps[j];
                const f2 vl = (n >= 0) ? pc[n] : lw[20 + n];
                acc -= cw[j] * vl;
                const int m = i + taps[j];
                if (m <= 7) acc -= cw[j] * pc[m];
            }
            H[i] = acc;
        }
    }
    {   // ---- pass R: right window (d0+7, d0+28) ----
        f2 rw2[20];
#pragma unroll
        for (int k = 0; k < 10; ++k) {
            float4 v = *reinterpret_cast<const float4*>(&lds[raR[k]]);
            rw2[2 * k] = f2{v.x, v.y};
            rw2[2 * k + 1] = f2{v.z, v.w};
        }
#pragma unroll
        for (int i = 0; i < 8; ++i) {
            f2 acc = H[i];
#pragma unroll
            for (int j = 0; j < 11; ++j) {
                const int m = i + taps[j];
                if (m > 7) acc -= cw[j] * rw2[m - 8];
            }
            H[i] = acc;
        }
    }
}

// Store this thread's 8 interleaved complex (4 float4) + halo copies
// (threads 0..3 duplicate right, 124..127 left).
__device__ __forceinline__ void store_row8p(float* lds, const int wa[4], const int ha[4],
                                            bool hh, const f2 v[8]) {
#pragma unroll
    for (int j = 0; j < 4; ++j) {
        float4 a = make_float4(v[2 * j].x, v[2 * j].y, v[2 * j + 1].x, v[2 * j + 1].y);
        *reinterpret_cast<float4*>(&lds[wa[j]]) = a;
        if (hh) *reinterpret_cast<float4*>(&lds[ha[j]]) = a;
    }
}

__global__ void __launch_bounds__(128, 2)
cayley_kernel(const float* __restrict__ psi_r, const float* __restrict__ psi_i,
              const float* __restrict__ alpha, const float* __restrict__ sw,
              const float* __restrict__ potential, float* __restrict__ out) {
    __shared__ __align__(16) float lds[IMGF];   // one row, interleaved complex
    __shared__ float red0[2], red1[2];

    const int u = threadIdx.x;     // 0..127; owns complex [8u, 8u+8)
    const int wave = u >> 6;
    const int row = blockIdx.x;

    const float w0 = sw[0], w1 = sw[1], w2 = sw[2];   // uniform -> SGPRs
    const float cw[11] = {w0, w0 + w1, w0, w0 + w1 + w2, w0, w1, w1 + w2, w1, w2, w2, w2};
    const float dadd = 10.0f * (w0 + w1 + w2);

    // Loop-invariant swizzled LDS float-index addresses.
    const int fb = 2 * (HALO + 8 * u);   // float index of this thread's first complex
    int wa[4], raL[10], raR[10];
#pragma unroll
    for (int j = 0; j < 4; ++j) wa[j] = swzf(fb + 4 * j);
#pragma unroll
    for (int k = 0; k < 10; ++k) {
        raL[k] = swzf(fb - 40 + 4 * k);       // left 20 complex
        raR[k] = swzf(fb + 16 + 4 * k);       // right 20 complex
    }
    const bool hh = (u < 4) || (u >= 124);
    int ha[4] = {0, 0, 0, 0};
    if (u < 4) {
#pragma unroll
        for (int j = 0; j < 4; ++j) ha[j] = swzf(fb + 2 * DD + 4 * j);
    } else if (u >= 124) {
#pragma unroll
        for (int j = 0; j < 4; ++j) ha[j] = swzf(fb - 2 * DD + 4 * j);
    }

    // --- global loads: 8 complex per thread (planar in, packed regs) ---
    const size_t goff = (size_t)row * DD + 8 * u;
    f2 cur[8];
    float diag[8];
#pragma unroll
    for (int j = 0; j < 2; ++j) {
        float4 a = *reinterpret_cast<const float4*>(psi_r + goff + 4 * j);
        float4 b = *reinterpret_cast<const float4*>(psi_i + goff + 4 * j);
        float4 d = *reinterpret_cast<const float4*>(potential + 8 * u + 4 * j);
        cur[4 * j + 0] = f2{a.x, b.x};
        cur[4 * j + 1] = f2{a.y, b.y};
        cur[4 * j + 2] = f2{a.z, b.z};
        cur[4 * j + 3] = f2{a.w, b.w};
        diag[4 * j] = d.x + dadd; diag[4 * j + 1] = d.y + dadd;
        diag[4 * j + 2] = d.z + dadd; diag[4 * j + 3] = d.w + dadd;
    }

    // --- intensity mean over the row ---
    float isum = 0.f;
#pragma unroll
    for (int i = 0; i < 8; ++i) isum += cur[i].x * cur[i].x + cur[i].y * cur[i].y;
    const float tot = row_sum(isum, red0, wave);
    const float inv_mean = 1.0f / (tot * (1.0f / DD) + 1e-8f);

    // --- nonlinear phase rotation (in place) ---
#pragma unroll
    for (int j = 0; j < 2; ++j) {
        float4 c = *reinterpret_cast<const float4*>(alpha + 8 * u + 4 * j);
        float av[4] = {c.x, c.y, c.z, c.w};
#pragma unroll
        for (int q = 0; q < 4; ++q) {
            const int i = 4 * j + q;
            const float ph = av[q] * ((cur[i].x * cur[i].x + cur[i].y * cur[i].y) * inv_mean);
            float s, cc;
            __sincosf(ph, &s, &cc);
            cur[i] = f2{cur[i].x * cc - cur[i].y * s, cur[i].x * s + cur[i].y * cc};
        }
    }

    store_row8p(lds, wa, ha, hh, cur);
    __syncthreads();

    // --- rhs = (I - i*h*H) rot ; r = p = rhs ; x = 0 ---
    f2 H2[8];
    hmat8p(lds, raL, raR, cw, diag, cur, H2);

    f2 x2[8], r2[8], p2[8];
    float rsum = 0.f;
#pragma unroll
    for (int i = 0; i < 8; ++i) {
        x2[i] = f2{0.f, 0.f};
        r2[i] = f2{cur[i].x + HALF_DT_F * H2[i].y, cur[i].y - HALF_DT_F * H2[i].x};
        p2[i] = r2[i];
        rsum += r2[i].x * r2[i].x + r2[i].y * r2[i].y;
    }
    float rs = row_sum(rsum, red1, wave);   // barrier fences rot-window reads

    store_row8p(lds, wa, ha, hh, p2);
    __syncthreads();

    // --- CG: 20 fixed iterations, 3 barriers each ---
#pragma unroll 1
    for (int it = 0; it < CG_ITERS_N; ++it) {
        hmat8p(lds, raL, raR, cw, diag, p2, H2);

        // Ap = (pr - h*Hi, pi + h*Hr); packed dot p.Ap
        f2 Ap2[8];
        f2 papv = f2{0.f, 0.f};
#pragma unroll
        for (int i = 0; i < 8; ++i) {
            Ap2[i] = f2{p2[i].x - HALF_DT_F * H2[i].y, p2[i].y + HALF_DT_F * H2[i].x};
            papv += p2[i] * Ap2[i];
        }
        const float pAp = row_sum(papv.x + papv.y, red0, wave);   // barrier #1
        const float al = rs / (pAp + 1e-12f);

        f2 rnv = f2{0.f, 0.f};
#pragma unroll
        for (int i = 0; i < 8; ++i) {
            x2[i] += al * p2[i];
            r2[i] -= al * Ap2[i];
            rnv += r2[i] * r2[i];
        }
        const float rs_new = row_sum(rnv.x + rnv.y, red1, wave);  // barrier #2
        const float beta = rs_new / (rs + 1e-12f);
        rs = rs_new;
#pragma unroll
        for (int i = 0; i < 8; ++i) p2[i] = r2[i] + beta * p2[i];

        store_row8p(lds, wa, ha, hh, p2);
        __syncthreads();                                          // barrier #3
    }

    // --- write x: output layout [.., D, 2] is exactly our packed layout ---
    float* op = out + 2 * goff;
#pragma unroll
    for (int j = 0; j < 4; ++j) {
        *reinterpret_cast<float4*>(op + 4 * j) =
            make_float4(x2[2 * j].x, x2[2 * j].y, x2[2 * j + 1].x, x2[2 * j + 1].y);
    }
}

extern "C" void kernel_launch(void* const* d_in, const int* in_sizes, int n_in,
                              void* d_out, int out_size, void* d_ws, size_t ws_size,
                              hipStream_t stream) {
    const float* psi_r = (const float*)d_in[0];
    const float* psi_i = (const float*)d_in[1];
    const float* alpha = (const float*)d_in[2];
    const float* sw = (const float*)d_in[3];
    const float* pot = (const float*)d_in[4];
    float* out = (float*)d_out;
    const int rows = in_sizes[0] / DD;   // B*S = 8192
    cayley_kernel<<<dim3(rows), dim3(128), 0, stream>>>(psi_r, psi_i, alpha, sw, pot, out);
}

// Round 11
// 279.466 us; speedup vs baseline: 1.1942x; 1.0391x over previous
//
#include <hip/hip_runtime.h>

#define DD 1024
#define HALO 32
#define IMGF (2 * (HALO + DD + HALO))   // floats per interleaved row image = 2176 = 17*128
#define HALF_DT_F 0.05f
#define CG_ITERS_N 20

typedef float f2 __attribute__((ext_vector_type(2)));   // (re, im) -> VGPR pair

// ---- forced packed-FP32 ops (VOP3P v_pk_fma_f32) ----
// d -= w * v, w = uniform SGPR pair {w,w}
__device__ __forceinline__ void pk_fnma_s(f2& d, unsigned long long w, f2 v) {
    asm("v_pk_fma_f32 %0, %1, %2, %0 neg_lo:[1,0,0] neg_hi:[1,0,0]"
        : "+v"(d) : "s"(w), "v"(v));
}
// d += a*b
__device__ __forceinline__ void pk_fma(f2& d, f2 a, f2 b) {
    asm("v_pk_fma_f32 %0, %1, %2, %0" : "+v"(d) : "v"(a), "v"(b));
}
// d -= a*b
__device__ __forceinline__ void pk_fnma(f2& d, f2 a, f2 b) {
    asm("v_pk_fma_f32 %0, %1, %2, %0 neg_lo:[1,0,0] neg_hi:[1,0,0]"
        : "+v"(d) : "v"(a), "v"(b));
}
// p = a*p + r
__device__ __forceinline__ void pk_fma_pr(f2& p, f2 a, f2 r) {
    asm("v_pk_fma_f32 %0, %1, %0, %2" : "+v"(p) : "v"(a), "v"(r));
}

// XOR swizzle on float index (byte' = byte ^ (((byte>>7)&3)<<4)).
// Involution; preserves 16B alignment; commutes with offsets that are
// multiples of 128 floats (512B): IMGF row base and +-2*DD halo shifts.
__device__ __forceinline__ int swzf(int f) { return f ^ (((f >> 5) & 3) << 2); }

// Wave64 sum via DPP (pure VALU). Total valid in lane 63 ONLY.
__device__ __forceinline__ float dpp_wave_sum(float v) {
    int b;
    b = __builtin_amdgcn_update_dpp(0, __float_as_int(v), 0x111, 0xf, 0xf, true); v += __int_as_float(b); // row_shr:1
    b = __builtin_amdgcn_update_dpp(0, __float_as_int(v), 0x112, 0xf, 0xf, true); v += __int_as_float(b); // row_shr:2
    b = __builtin_amdgcn_update_dpp(0, __float_as_int(v), 0x114, 0xf, 0xf, true); v += __int_as_float(b); // row_shr:4
    b = __builtin_amdgcn_update_dpp(0, __float_as_int(v), 0x118, 0xf, 0xf, true); v += __int_as_float(b); // row_shr:8
    b = __builtin_amdgcn_update_dpp(0, __float_as_int(v), 0x142, 0xa, 0xf, true); v += __int_as_float(b); // row_bcast:15
    b = __builtin_amdgcn_update_dpp(0, __float_as_int(v), 0x143, 0xc, 0xf, true); v += __int_as_float(b); // row_bcast:31
    return v;
}

// Row-wide (128-thread, 2-wave) sum; exactly one barrier.
__device__ __forceinline__ float row_sum(float v, float* red, int wave, int rw) {
    v = dpp_wave_sum(v);
    if ((threadIdx.x & 63) == 63) red[wave] = v;
    __syncthreads();
    return red[2 * rw] + red[2 * rw + 1];
}

// Packed H-apply on this thread's 8 complex elements (center in regs).
// 184 forced v_pk_fma_f32 with SGPR-pair weights.
__device__ __forceinline__ void hmat8p(const float* lds, const int raL[10], const int raR[10],
                                       const unsigned long long wp[11], const float diag[8],
                                       const f2 pc[8], f2 H[8]) {
    constexpr int taps[11] = {1, 2, 3, 4, 5, 6, 8, 10, 12, 16, 20};
    {   // ---- pass L: left window [d0-20, d0) + all center-resident taps ----
        f2 lw[20];
#pragma unroll
        for (int k = 0; k < 10; ++k) {
            float4 v = *reinterpret_cast<const float4*>(&lds[raL[k]]);
            lw[2 * k] = f2{v.x, v.y};
            lw[2 * k + 1] = f2{v.z, v.w};
        }
#pragma unroll
        for (int i = 0; i < 8; ++i) {
            f2 acc = f2{diag[i] * pc[i].x, diag[i] * pc[i].y};
#pragma unroll
            for (int j = 0; j < 11; ++j) {
                const int n = i - taps[j];
                pk_fnma_s(acc, wp[j], (n >= 0) ? pc[n] : lw[20 + n]);
                const int m = i + taps[j];
                if (m <= 7) pk_fnma_s(acc, wp[j], pc[m]);
            }
            H[i] = acc;
        }
    }
    {   // ---- pass R: right window (d0+7, d0+28) ----
        f2 rw2[20];
#pragma unroll
        for (int k = 0; k < 10; ++k) {
            float4 v = *reinterpret_cast<const float4*>(&lds[raR[k]]);
            rw2[2 * k] = f2{v.x, v.y};
            rw2[2 * k + 1] = f2{v.z, v.w};
        }
#pragma unroll
        for (int i = 0; i < 8; ++i) {
#pragma unroll
            for (int j = 0; j < 11; ++j) {
                const int m = i + taps[j];
                if (m > 7) pk_fnma_s(H[i], wp[j], rw2[m - 8]);
            }
        }
    }
}

// Store this thread's 8 interleaved complex (4 float4) + halo copies.
__device__ __forceinline__ void store_row8p(float* lds, const int wa[4], const int ha[4],
                                            bool hh, const f2 v[8]) {
#pragma unroll
    for (int j = 0; j < 4; ++j) {
        float4 a = make_float4(v[2 * j].x, v[2 * j].y, v[2 * j + 1].x, v[2 * j + 1].y);
        *reinterpret_cast<float4*>(&lds[wa[j]]) = a;
        if (hh) *reinterpret_cast<float4*>(&lds[ha[j]]) = a;
    }
}

__global__ void __launch_bounds__(256, 2)
cayley_kernel(const float* __restrict__ psi_r, const float* __restrict__ psi_i,
              const float* __restrict__ alpha, const float* __restrict__ sw,
              const float* __restrict__ potential, float* __restrict__ out) {
    __shared__ __align__(16) float lds[2 * IMGF];   // 2 rows, interleaved complex
    __shared__ float red0[4], red1[4];

    const int t = threadIdx.x;
    const int u = t & 127;         // row-local thread: owns complex [8u, 8u+8)
    const int rw = t >> 7;         // row within block (0/1)
    const int wave = t >> 6;
    const int rb = rw * IMGF;
    const int row = (blockIdx.x << 1) + rw;

    const float w0 = sw[0], w1 = sw[1], w2 = sw[2];
    const float cwv[11] = {w0, w0 + w1, w0, w0 + w1 + w2, w0, w1, w1 + w2, w1, w2, w2, w2};
    const float dadd = 10.0f * (w0 + w1 + w2);

    // Uniform weight pairs {w,w} in SGPR pairs: explicit readfirstlane makes
    // the value provably uniform (legal for the "s" asm constraint); the
    // 64-bit shift/or then stays in SALU.
    unsigned long long wp[11];
#pragma unroll
    for (int j = 0; j < 11; ++j) {
        const unsigned int b = __builtin_amdgcn_readfirstlane(__float_as_uint(cwv[j]));
        wp[j] = ((unsigned long long)b << 32) | b;
    }

    // Loop-invariant swizzled LDS float-index addresses.
    const int fb = rb + 2 * (HALO + 8 * u);
    int wa[4], raL[10], raR[10];
#pragma unroll
    for (int j = 0; j < 4; ++j) wa[j] = swzf(fb + 4 * j);
#pragma unroll
    for (int k = 0; k < 10; ++k) {
        raL[k] = swzf(fb - 40 + 4 * k);       // left 20 complex
        raR[k] = swzf(fb + 16 + 4 * k);       // right 20 complex
    }
    const bool hh = (u < 4) || (u >= 124);
    int ha[4] = {0, 0, 0, 0};
    if (u < 4) {
#pragma unroll
        for (int j = 0; j < 4; ++j) ha[j] = swzf(fb + 2 * DD + 4 * j);
    } else if (u >= 124) {
#pragma unroll
        for (int j = 0; j < 4; ++j) ha[j] = swzf(fb - 2 * DD + 4 * j);
    }

    // --- global loads: 8 complex per thread (planar in, packed regs) ---
    const size_t goff = (size_t)row * DD + 8 * u;
    f2 cur[8];
    float diag[8];
#pragma unroll
    for (int j = 0; j < 2; ++j) {
        float4 a = *reinterpret_cast<const float4*>(psi_r + goff + 4 * j);
        float4 b = *reinterpret_cast<const float4*>(psi_i + goff + 4 * j);
        float4 d = *reinterpret_cast<const float4*>(potential + 8 * u + 4 * j);
        cur[4 * j + 0] = f2{a.x, b.x};
        cur[4 * j + 1] = f2{a.y, b.y};
        cur[4 * j + 2] = f2{a.z, b.z};
        cur[4 * j + 3] = f2{a.w, b.w};
        diag[4 * j] = d.x + dadd; diag[4 * j + 1] = d.y + dadd;
        diag[4 * j + 2] = d.z + dadd; diag[4 * j + 3] = d.w + dadd;
    }

    // --- intensity mean over the row ---
    float isum = 0.f;
#pragma unroll
    for (int i = 0; i < 8; ++i) isum += cur[i].x * cur[i].x + cur[i].y * cur[i].y;
    const float tot = row_sum(isum, red0, wave, rw);
    const float inv_mean = 1.0f / (tot * (1.0f / DD) + 1e-8f);

    // --- nonlinear phase rotation (in place) ---
#pragma unroll
    for (int j = 0; j < 2; ++j) {
        float4 c = *reinterpret_cast<const float4*>(alpha + 8 * u + 4 * j);
        float av[4] = {c.x, c.y, c.z, c.w};
#pragma unroll
        for (int q = 0; q < 4; ++q) {
            const int i = 4 * j + q;
            const float ph = av[q] * ((cur[i].x * cur[i].x + cur[i].y * cur[i].y) * inv_mean);
            float s, cc;
            __sincosf(ph, &s, &cc);
            cur[i] = f2{cur[i].x * cc - cur[i].y * s, cur[i].x * s + cur[i].y * cc};
        }
    }

    store_row8p(lds, wa, ha, hh, cur);
    __syncthreads();

    // --- rhs = (I - i*h*H) rot ; r = p = rhs ; x = 0 ---
    f2 H2[8];
    hmat8p(lds, raL, raR, wp, diag, cur, H2);

    f2 x2[8], r2[8], p2[8];
    float rsum = 0.f;
#pragma unroll
    for (int i = 0; i < 8; ++i) {
        x2[i] = f2{0.f, 0.f};
        r2[i] = f2{cur[i].x + HALF_DT_F * H2[i].y, cur[i].y - HALF_DT_F * H2[i].x};
        p2[i] = r2[i];
        rsum += r2[i].x * r2[i].x + r2[i].y * r2[i].y;
    }
    float rs = row_sum(rsum, red1, wave, rw);   // barrier fences rot-window reads

    store_row8p(lds, wa, ha, hh, p2);
    __syncthreads();

    // --- CG: 20 fixed iterations, 3 barriers each ---
#pragma unroll 1
    for (int it = 0; it < CG_ITERS_N; ++it) {
        hmat8p(lds, raL, raR, wp, diag, p2, H2);

        // Ap = (pr - h*Hi, pi + h*Hr); packed dot p.Ap
        f2 Ap2[8];
        f2 papv = f2{0.f, 0.f};
#pragma unroll
        for (int i = 0; i < 8; ++i) {
            Ap2[i] = f2{p2[i].x - HALF_DT_F * H2[i].y, p2[i].y + HALF_DT_F * H2[i].x};
            pk_fma(papv, p2[i], Ap2[i]);
        }
        const float pAp = row_sum(papv.x + papv.y, red0, wave, rw);   // barrier #1
        const float al = rs / (pAp + 1e-12f);
        const f2 alp = f2{al, al};

        f2 rnv = f2{0.f, 0.f};
#pragma unroll
        for (int i = 0; i < 8; ++i) {
            pk_fma(x2[i], alp, p2[i]);
            pk_fnma(r2[i], alp, Ap2[i]);
            pk_fma(rnv, r2[i], r2[i]);
        }
        const float rs_new = row_sum(rnv.x + rnv.y, red1, wave, rw);  // barrier #2
        const float beta = rs_new / (rs + 1e-12f);
        rs = rs_new;
        const f2 bp = f2{beta, beta};
#pragma unroll
        for (int i = 0; i < 8; ++i) pk_fma_pr(p2[i], bp, r2[i]);      // p = beta*p + r

        store_row8p(lds, wa, ha, hh, p2);
        __syncthreads();                                              // barrier #3
    }

    // --- write x: output layout [.., D, 2] is exactly our packed layout ---
    float* op = out + 2 * goff;
#pragma unroll
    for (int j = 0; j < 4; ++j) {
        *reinterpret_cast<float4*>(op + 4 * j) =
            make_float4(x2[2 * j].x, x2[2 * j].y, x2[2 * j + 1].x, x2[2 * j + 1].y);
    }
}

extern "C" void kernel_launch(void* const* d_in, const int* in_sizes, int n_in,
                              void* d_out, int out_size, void* d_ws, size_t ws_size,
                              hipStream_t stream) {
    const float* psi_r = (const float*)d_in[0];
    const float* psi_i = (const float*)d_in[1];
    const float* alpha = (const float*)d_in[2];
    const float* sw = (const float*)d_in[3];
    const float* pot = (const float*)d_in[4];
    float* out = (float*)d_out;
    const int rows = in_sizes[0] / DD;   // B*S = 8192
    cayley_kernel<<<dim3(rows / 2), dim3(256), 0, stream>>>(psi_r, psi_i, alpha, sw, pot, out);
}